// Round 10
// baseline (445.780 us; speedup 1.0000x reference)
//
#include <hip/hip_runtime.h>

#define CUTOFF 1.6f
#define BLOCK 256
#define EPT 4
#define EPB (BLOCK * EPT)

typedef float f32x4 __attribute__((ext_vector_type(4)));

// K1: read Rij (float4), write Rij passthrough, per-block counts.
// Plain stores; cross-kernel visibility via the dispatch boundary.
__global__ void __launch_bounds__(BLOCK) k1_count_copy(
    const float* __restrict__ Rij, float* __restrict__ outRij,
    int* __restrict__ counts, long E)
{
  long b = blockIdx.x;
  int t = threadIdx.x;
  long base = b * (long)EPB + (long)t * EPT;
  int cnt = 0;
  if (base < E) {  // E % 4 == 0 -> thread has all 4 edges or none
    const f32x4* rp4 = (const f32x4*)(Rij + base * 3);
    f32x4* op4 = (f32x4*)(outRij + base * 3);
    float rr[12];
#pragma unroll
    for (int q = 0; q < 3; ++q) {
      f32x4 v = rp4[q];
      op4[q] = v;
      rr[4 * q + 0] = v.x; rr[4 * q + 1] = v.y;
      rr[4 * q + 2] = v.z; rr[4 * q + 3] = v.w;
    }
#pragma unroll
    for (int k = 0; k < EPT; ++k) {
      float x = rr[3 * k], y = rr[3 * k + 1], z = rr[3 * k + 2];
      float s = sqrtf(x * x + y * y + z * z);
      cnt += (s <= CUTOFF) ? 1 : 0;
    }
  }
#pragma unroll
  for (int d = 32; d > 0; d >>= 1) cnt += __shfl_down(cnt, d, 64);
  __shared__ int ssum;
  if (t == 0) ssum = 0;
  __syncthreads();
  if ((t & 63) == 0) atomicAdd(&ssum, cnt);
  __syncthreads();
  if (t == 0) counts[b] = ssum;
}

// cooperative aligned copy: dst[0..len) = src[0..len), float4 interior
__device__ __forceinline__ void coop_copy(float* __restrict__ dst,
                                          const float* __restrict__ src,
                                          int len, int t)
{
  int h = (int)(((16u - (unsigned)((unsigned long long)dst & 15ull)) >> 2) & 3u);
  if (h > len) h = len;
  if (t < h) dst[t] = src[t];
  int n4 = (len - h) >> 2;
  f32x4* d4 = (f32x4*)(dst + h);
  for (int q = t; q < n4; q += BLOCK) {
    int s = h + 4 * q;
    f32x4 v = {src[s], src[s + 1], src[s + 2], src[s + 3]};
    d4[q] = v;
  }
  int done = h + 4 * n4;
  int rem = len - done;
  if (t < rem) dst[done + t] = src[done + t];
}

// cooperative aligned constant fill over absolute float range [lo,hi)
__device__ __forceinline__ void coop_fill(float* __restrict__ base, long lo,
                                          long hi, float val, int t)
{
  long len = hi - lo;
  if (len <= 0) return;
  float* p = base + lo;
  int h = (int)(((16u - (unsigned)((unsigned long long)p & 15ull)) >> 2) & 3u);
  if ((long)h > len) h = (int)len;
  if (t < h) p[t] = val;
  long n4 = (len - h) >> 2;
  f32x4* d4 = (f32x4*)(p + h);
  f32x4 v = {val, val, val, val};
  for (long q = t; q < n4; q += BLOCK) d4[q] = v;
  long done = h + 4 * n4;
  int rem = (int)(len - done);
  if (t < rem) p[done + t] = val;
}

// K3: issue input loads; compute (prefix, total) of counts via one packed
// u64 block-reduction (overlaps the in-flight loads); idx passthrough;
// mask + block scan; LDS-staged compaction; aligned cooperative writes;
// pad fills. No k2 dispatch needed.
__global__ void __launch_bounds__(BLOCK) k3_all(
    const float* __restrict__ Rij, const int* __restrict__ idx_i,
    const int* __restrict__ idx_j, const int* __restrict__ counts,
    float* __restrict__ out, long E, int nb)
{
  long b = blockIdx.x;
  int t = threadIdx.x;
  int lane = t & 63, wid = t >> 6;
  long base = b * (long)EPB + (long)t * EPT;

  __shared__ float sR[3 * EPB];  // 12 KB
  __shared__ float sI[EPB];      // 4 KB
  __shared__ float sJ[EPB];      // 4 KB
  __shared__ int wsum[BLOCK / 64];
  __shared__ unsigned long long wpt[BLOCK / 64];

  // issue the block's input loads (consumed after the counts loop)
  f32x4 r0 = {}, r1 = {}, r2 = {};
  int4 ia = {}, ja = {};
  if (base < E) {
    const f32x4* rp4 = (const f32x4*)(Rij + base * 3);
    r0 = rp4[0]; r1 = rp4[1]; r2 = rp4[2];
    ia = *(const int4*)(idx_i + base);
    ja = *(const int4*)(idx_j + base);
  }

  // (prefix, total) of counts: packed u64, carry-free (both < 2^32)
  unsigned long long pt = 0;
  for (int i = t; i < nb; i += BLOCK) {
    unsigned c = (unsigned)counts[i];
    pt += ((unsigned long long)c << 32) | (i < (int)b ? c : 0u);
  }
#pragma unroll
  for (int d = 32; d > 0; d >>= 1) pt += __shfl_down(pt, d, 64);
  if (lane == 0) wpt[wid] = pt;
  __syncthreads();
  unsigned long long ptot = 0;
#pragma unroll
  for (int w = 0; w < BLOCK / 64; ++w) ptot += wpt[w];
  long off = (long)(unsigned)(ptot & 0xFFFFFFFFull);  // sum counts[0..b)
  long n = (long)(unsigned)(ptot >> 32);              // n_sr
  if (b == 0 && t == 0) out[10 * E] = (float)n;

  float rr[12];
  int ii[EPT], jj[EPT];
  unsigned m = 0;
  int cnt = 0;
  if (base < E) {
    rr[0] = r0.x; rr[1] = r0.y; rr[2] = r0.z; rr[3] = r0.w;
    rr[4] = r1.x; rr[5] = r1.y; rr[6] = r1.z; rr[7] = r1.w;
    rr[8] = r2.x; rr[9] = r2.y; rr[10] = r2.z; rr[11] = r2.w;
    ii[0] = ia.x; ii[1] = ia.y; ii[2] = ia.z; ii[3] = ia.w;
    jj[0] = ja.x; jj[1] = ja.y; jj[2] = ja.z; jj[3] = ja.w;
    // idx passthrough as float values (normal float4 stores)
    f32x4 fi0 = {(float)ii[0], (float)ii[1], (float)ii[2], (float)ii[3]};
    f32x4 fj0 = {(float)jj[0], (float)jj[1], (float)jj[2], (float)jj[3]};
    *(f32x4*)(out + 3 * E + base) = fi0;
    *(f32x4*)(out + 4 * E + base) = fj0;
#pragma unroll
    for (int k = 0; k < EPT; ++k) {
      float x = rr[3 * k], y = rr[3 * k + 1], z = rr[3 * k + 2];
      float s = sqrtf(x * x + y * y + z * z);
      if (s <= CUTOFF) { m |= 1u << k; ++cnt; }
    }
  }

  // block scan of per-thread counts
  int sv = cnt;
#pragma unroll
  for (int d = 1; d < 64; d <<= 1) {
    int nn = __shfl_up(sv, d, 64);
    if (lane >= d) sv += nn;
  }
  if (lane == 63) wsum[wid] = sv;
  __syncthreads();
  int woff = 0, bsum = 0;
#pragma unroll
  for (int w = 0; w < BLOCK / 64; ++w) {
    int s = wsum[w];
    if (w < wid) woff += s;
    bsum += s;
  }
  int texcl = woff + sv - cnt;  // thread's exclusive offset within block

  // stage compacted edges into LDS in stable order
  if (base < E && m) {
    int p = texcl;
#pragma unroll
    for (int k = 0; k < EPT; ++k) {
      if (m & (1u << k)) {
        sR[3 * p + 0] = rr[3 * k + 0];
        sR[3 * p + 1] = rr[3 * k + 1];
        sR[3 * p + 2] = rr[3 * k + 2];
        sI[p] = (float)ii[k];
        sJ[p] = (float)jj[k];
        ++p;
      }
    }
  }
  __syncthreads();

  // cooperative aligned writes of the block's three contiguous runs
  coop_copy(out + 5 * E + 3 * off, sR, 3 * bsum, t);
  coop_copy(out + 8 * E + off, sI, bsum, t);
  coop_copy(out + 9 * E + off, sJ, bsum, t);

  // pad fills: three flat constant ranges, sliced across blocks, float4.
  {
    long len = 3 * (E - n);
    long share = ((len + nb - 1) / nb + 3) & ~3L;
    long lo = 5 * E + 3 * n + b * share;
    long hi = lo + share;
    long cap = 8 * E;
    if (hi > cap) hi = cap;
    coop_fill(out, lo, hi, 0.0f, t);
  }
  {
    long len = E - n;
    long share = ((len + nb - 1) / nb + 3) & ~3L;
    long lo = 8 * E + n + b * share;
    long hi = lo + share;
    long cap = 9 * E;
    if (hi > cap) hi = cap;
    coop_fill(out, lo, hi, -1.0f, t);
  }
  {
    long len = E - n;
    long share = ((len + nb - 1) / nb + 3) & ~3L;
    long lo = 9 * E + n + b * share;
    long hi = lo + share;
    long cap = 10 * E;
    if (hi > cap) hi = cap;
    coop_fill(out, lo, hi, -1.0f, t);
  }
}

extern "C" void kernel_launch(void* const* d_in, const int* in_sizes, int n_in,
                              void* d_out, int out_size, void* d_ws,
                              size_t ws_size, hipStream_t stream)
{
  const float* Rij = (const float*)d_in[0];
  const int* idx_i = (const int*)d_in[1];
  const int* idx_j = (const int*)d_in[2];
  long E = (long)in_sizes[1];
  float* out = (float*)d_out;

  int nb = (int)((E + EPB - 1) / EPB);
  int* counts = (int*)d_ws;  // nb ints, fully rewritten by K1 every call

  k1_count_copy<<<nb, BLOCK, 0, stream>>>(Rij, out, counts, E);
  k3_all<<<nb, BLOCK, 0, stream>>>(Rij, idx_i, idx_j, counts, out, E, nb);
}

// Round 11
// 359.070 us; speedup vs baseline: 1.2415x; 1.2415x over previous
//
#include <hip/hip_runtime.h>

#define CUTOFF 1.6f
#define BLOCK 256
#define EPT 4
#define EPB (BLOCK * EPT)
#define SB_LOG 8  // 256 blocks per superblock

typedef float f32x4 __attribute__((ext_vector_type(4)));

// K1: read Rij (float4), write Rij passthrough, per-block counts + one
// superblock atomicAdd (order-independent => deterministic). Plain stores;
// cross-kernel visibility via the dispatch boundary (no fences - R8 lesson).
__global__ void __launch_bounds__(BLOCK) k1_count_copy(
    const float* __restrict__ Rij, float* __restrict__ outRij,
    int* __restrict__ counts, int* __restrict__ sbsum, long E)
{
  long b = blockIdx.x;
  int t = threadIdx.x;
  long base = b * (long)EPB + (long)t * EPT;
  int cnt = 0;
  if (base < E) {  // E % 4 == 0 -> thread has all 4 edges or none
    const f32x4* rp4 = (const f32x4*)(Rij + base * 3);
    f32x4* op4 = (f32x4*)(outRij + base * 3);
    float rr[12];
#pragma unroll
    for (int q = 0; q < 3; ++q) {
      f32x4 v = rp4[q];
      op4[q] = v;
      rr[4 * q + 0] = v.x; rr[4 * q + 1] = v.y;
      rr[4 * q + 2] = v.z; rr[4 * q + 3] = v.w;
    }
#pragma unroll
    for (int k = 0; k < EPT; ++k) {
      float x = rr[3 * k], y = rr[3 * k + 1], z = rr[3 * k + 2];
      float s = sqrtf(x * x + y * y + z * z);
      cnt += (s <= CUTOFF) ? 1 : 0;
    }
  }
#pragma unroll
  for (int d = 32; d > 0; d >>= 1) cnt += __shfl_down(cnt, d, 64);
  __shared__ int ssum;
  if (t == 0) ssum = 0;
  __syncthreads();
  if ((t & 63) == 0) atomicAdd(&ssum, cnt);
  __syncthreads();
  if (t == 0) {
    counts[b] = ssum;
    atomicAdd(&sbsum[b >> SB_LOG], ssum);  // device-scope, commutative
  }
}

// cooperative aligned copy: dst[0..len) = src[0..len), float4 interior
__device__ __forceinline__ void coop_copy(float* __restrict__ dst,
                                          const float* __restrict__ src,
                                          int len, int t)
{
  int h = (int)(((16u - (unsigned)((unsigned long long)dst & 15ull)) >> 2) & 3u);
  if (h > len) h = len;
  if (t < h) dst[t] = src[t];
  int n4 = (len - h) >> 2;
  f32x4* d4 = (f32x4*)(dst + h);
  for (int q = t; q < n4; q += BLOCK) {
    int s = h + 4 * q;
    f32x4 v = {src[s], src[s + 1], src[s + 2], src[s + 3]};
    d4[q] = v;
  }
  int done = h + 4 * n4;
  int rem = len - done;
  if (t < rem) dst[done + t] = src[done + t];
}

// cooperative aligned constant fill over absolute float range [lo,hi)
__device__ __forceinline__ void coop_fill(float* __restrict__ base, long lo,
                                          long hi, float val, int t)
{
  long len = hi - lo;
  if (len <= 0) return;
  float* p = base + lo;
  int h = (int)(((16u - (unsigned)((unsigned long long)p & 15ull)) >> 2) & 3u);
  if ((long)h > len) h = (int)len;
  if (t < h) p[t] = val;
  long n4 = (len - h) >> 2;
  f32x4* d4 = (f32x4*)(p + h);
  f32x4 v = {val, val, val, val};
  for (long q = t; q < n4; q += BLOCK) d4[q] = v;
  long done = h + 4 * n4;
  int rem = (int)(len - done);
  if (t < rem) p[done + t] = val;
}

// K3: input loads; self-computed (prefix, total) via superblock sums +
// short within-superblock partial (aggregate ~20 MB - overlaps load
// latency); idx passthrough; mask + block scan; LDS-staged compaction;
// aligned cooperative writes; pad fills last (R7 ordering).
__global__ void __launch_bounds__(BLOCK) k3_all(
    const float* __restrict__ Rij, const int* __restrict__ idx_i,
    const int* __restrict__ idx_j, const int* __restrict__ counts,
    const int* __restrict__ sbsum, float* __restrict__ out, long E,
    int nb, int nsb)
{
  long b = blockIdx.x;
  int t = threadIdx.x;
  int lane = t & 63, wid = t >> 6;
  long base = b * (long)EPB + (long)t * EPT;

  __shared__ float sR[3 * EPB];  // 12 KB
  __shared__ float sI[EPB];      // 4 KB
  __shared__ float sJ[EPB];      // 4 KB
  __shared__ int wsum[BLOCK / 64];
  __shared__ unsigned long long wpt[BLOCK / 64];

  float rr[12];
  int ii[EPT], jj[EPT];
  unsigned m = 0;
  int cnt = 0;
  if (base < E) {
    const f32x4* rp4 = (const f32x4*)(Rij + base * 3);
    f32x4 r0 = rp4[0], r1 = rp4[1], r2 = rp4[2];
    int4 ia = *(const int4*)(idx_i + base);
    int4 ja = *(const int4*)(idx_j + base);
    rr[0] = r0.x; rr[1] = r0.y; rr[2] = r0.z; rr[3] = r0.w;
    rr[4] = r1.x; rr[5] = r1.y; rr[6] = r1.z; rr[7] = r1.w;
    rr[8] = r2.x; rr[9] = r2.y; rr[10] = r2.z; rr[11] = r2.w;
    ii[0] = ia.x; ii[1] = ia.y; ii[2] = ia.z; ii[3] = ia.w;
    jj[0] = ja.x; jj[1] = ja.y; jj[2] = ja.z; jj[3] = ja.w;
    // idx passthrough as float values (normal float4 stores)
    f32x4 fi0 = {(float)ii[0], (float)ii[1], (float)ii[2], (float)ii[3]};
    f32x4 fj0 = {(float)jj[0], (float)jj[1], (float)jj[2], (float)jj[3]};
    *(f32x4*)(out + 3 * E + base) = fi0;
    *(f32x4*)(out + 4 * E + base) = fj0;
#pragma unroll
    for (int k = 0; k < EPT; ++k) {
      float x = rr[3 * k], y = rr[3 * k + 1], z = rr[3 * k + 2];
      float s = sqrtf(x * x + y * y + z * z);
      if (s <= CUTOFF) { m |= 1u << k; ++cnt; }
    }
  }

  // (prefix, total): packed u64, carry-free (both < 2^32)
  int sb = (int)(b >> SB_LOG);
  int sb_base = sb << SB_LOG;
  unsigned long long pt = 0;
  for (int s = t; s < nsb; s += BLOCK) {
    unsigned c = (unsigned)sbsum[s];
    pt += ((unsigned long long)c << 32) | (s < sb ? c : 0u);
  }
  for (int i = sb_base + t; i < (int)b; i += BLOCK)
    pt += (unsigned)counts[i];
#pragma unroll
  for (int d = 32; d > 0; d >>= 1) pt += __shfl_down(pt, d, 64);
  if (lane == 0) wpt[wid] = pt;

  // block scan of per-thread mask counts
  int sv = cnt;
#pragma unroll
  for (int d = 1; d < 64; d <<= 1) {
    int nn = __shfl_up(sv, d, 64);
    if (lane >= d) sv += nn;
  }
  if (lane == 63) wsum[wid] = sv;
  __syncthreads();
  unsigned long long ptot = 0;
  int woff = 0, bsum = 0;
#pragma unroll
  for (int w = 0; w < BLOCK / 64; ++w) {
    ptot += wpt[w];
    int s = wsum[w];
    if (w < wid) woff += s;
    bsum += s;
  }
  long off = (long)(unsigned)(ptot & 0xFFFFFFFFull);  // sum counts[0..b)
  long n = (long)(unsigned)(ptot >> 32);              // n_sr
  if (b == 0 && t == 0) out[10 * E] = (float)n;
  int texcl = woff + sv - cnt;  // thread's exclusive offset within block

  // stage compacted edges into LDS in stable order
  if (base < E && m) {
    int p = texcl;
#pragma unroll
    for (int k = 0; k < EPT; ++k) {
      if (m & (1u << k)) {
        sR[3 * p + 0] = rr[3 * k + 0];
        sR[3 * p + 1] = rr[3 * k + 1];
        sR[3 * p + 2] = rr[3 * k + 2];
        sI[p] = (float)ii[k];
        sJ[p] = (float)jj[k];
        ++p;
      }
    }
  }
  __syncthreads();

  // cooperative aligned writes of the block's three contiguous runs
  coop_copy(out + 5 * E + 3 * off, sR, 3 * bsum, t);
  coop_copy(out + 8 * E + off, sI, bsum, t);
  coop_copy(out + 9 * E + off, sJ, bsum, t);

  // pad fills: three flat constant ranges, sliced across blocks, float4.
  {
    long len = 3 * (E - n);
    long share = ((len + nb - 1) / nb + 3) & ~3L;
    long lo = 5 * E + 3 * n + b * share;
    long hi = lo + share;
    long cap = 8 * E;
    if (hi > cap) hi = cap;
    coop_fill(out, lo, hi, 0.0f, t);
  }
  {
    long len = E - n;
    long share = ((len + nb - 1) / nb + 3) & ~3L;
    long lo = 8 * E + n + b * share;
    long hi = lo + share;
    long cap = 9 * E;
    if (hi > cap) hi = cap;
    coop_fill(out, lo, hi, -1.0f, t);
  }
  {
    long len = E - n;
    long share = ((len + nb - 1) / nb + 3) & ~3L;
    long lo = 9 * E + n + b * share;
    long hi = lo + share;
    long cap = 10 * E;
    if (hi > cap) hi = cap;
    coop_fill(out, lo, hi, -1.0f, t);
  }
}

extern "C" void kernel_launch(void* const* d_in, const int* in_sizes, int n_in,
                              void* d_out, int out_size, void* d_ws,
                              size_t ws_size, hipStream_t stream)
{
  const float* Rij = (const float*)d_in[0];
  const int* idx_i = (const int*)d_in[1];
  const int* idx_j = (const int*)d_in[2];
  long E = (long)in_sizes[1];
  float* out = (float*)d_out;

  int nb = (int)((E + EPB - 1) / EPB);
  int nsb = (nb + (1 << SB_LOG) - 1) >> SB_LOG;
  int* counts = (int*)d_ws;    // nb ints, fully rewritten by K1 every call
  int* sbsum = counts + nb;    // nsb ints, atomicAdd targets

  hipMemsetAsync(sbsum, 0, (size_t)nsb * sizeof(int), stream);
  k1_count_copy<<<nb, BLOCK, 0, stream>>>(Rij, out, counts, sbsum, E);
  k3_all<<<nb, BLOCK, 0, stream>>>(Rij, idx_i, idx_j, counts, sbsum, out, E,
                                   nb, nsb);
}

// Round 12
// 317.285 us; speedup vs baseline: 1.4050x; 1.1317x over previous
//
#include <hip/hip_runtime.h>

#define CUTOFF 1.6f
#define BLOCK 256
#define EPT 4
#define EPB (BLOCK * EPT)

typedef float f32x4 __attribute__((ext_vector_type(4)));

// K1: READ-ONLY count pass. No bulk writes -> Rij stays fully resident in
// the 256MB L3 (Rij = 240MB fits) for K3's re-read. Copy-out moved to K3.
__global__ void __launch_bounds__(BLOCK) k1_count(
    const float* __restrict__ Rij, int* __restrict__ counts, long E)
{
  long b = blockIdx.x;
  int t = threadIdx.x;
  long base = b * (long)EPB + (long)t * EPT;
  int cnt = 0;
  if (base < E) {  // E % 4 == 0 -> thread has all 4 edges or none
    const f32x4* rp4 = (const f32x4*)(Rij + base * 3);
    f32x4 v0 = rp4[0], v1 = rp4[1], v2 = rp4[2];
    float rr[12];
    rr[0] = v0.x; rr[1] = v0.y; rr[2] = v0.z; rr[3] = v0.w;
    rr[4] = v1.x; rr[5] = v1.y; rr[6] = v1.z; rr[7] = v1.w;
    rr[8] = v2.x; rr[9] = v2.y; rr[10] = v2.z; rr[11] = v2.w;
#pragma unroll
    for (int k = 0; k < EPT; ++k) {
      float x = rr[3 * k], y = rr[3 * k + 1], z = rr[3 * k + 2];
      float s = sqrtf(x * x + y * y + z * z);
      cnt += (s <= CUTOFF) ? 1 : 0;
    }
  }
#pragma unroll
  for (int d = 32; d > 0; d >>= 1) cnt += __shfl_down(cnt, d, 64);
  __shared__ int ssum;
  if (t == 0) ssum = 0;
  __syncthreads();
  if ((t & 63) == 0) atomicAdd(&ssum, cnt);
  __syncthreads();
  if (t == 0) counts[b] = ssum;
}

// K2: single-block exclusive scan of block counts (in place); writes n_sr.
__global__ void __launch_bounds__(1024) k2_scan(
    int* __restrict__ counts, int nb, int* __restrict__ nsr,
    float* __restrict__ out_nsr)
{
  int t = threadIdx.x;
  int C = (nb + 1023) >> 10;
  int start = t * C;
  int end = min(start + C, nb);
  int sum = 0;
  for (int i = start; i < end; ++i) sum += counts[i];
  int lane = t & 63, wid = t >> 6;
  int v = sum;
#pragma unroll
  for (int d = 1; d < 64; d <<= 1) {
    int n = __shfl_up(v, d, 64);
    if (lane >= d) v += n;
  }
  __shared__ int wsum[16];
  if (lane == 63) wsum[wid] = v;
  __syncthreads();
  int woff = 0;
  for (int w = 0; w < wid; ++w) woff += wsum[w];
  int run = woff + v - sum;  // exclusive prefix of this thread
  for (int i = start; i < end; ++i) {
    int c = counts[i];
    counts[i] = run;
    run += c;
  }
  if (t == 1023) {  // run here == grand total
    nsr[0] = run;
    out_nsr[0] = (float)run;
  }
}

// cooperative aligned copy: dst[0..len) = src[0..len), float4 interior
__device__ __forceinline__ void coop_copy(float* __restrict__ dst,
                                          const float* __restrict__ src,
                                          int len, int t)
{
  int h = (int)(((16u - (unsigned)((unsigned long long)dst & 15ull)) >> 2) & 3u);
  if (h > len) h = len;
  if (t < h) dst[t] = src[t];
  int n4 = (len - h) >> 2;
  f32x4* d4 = (f32x4*)(dst + h);
  for (int q = t; q < n4; q += BLOCK) {
    int s = h + 4 * q;
    f32x4 v = {src[s], src[s + 1], src[s + 2], src[s + 3]};
    d4[q] = v;
  }
  int done = h + 4 * n4;
  int rem = len - done;
  if (t < rem) dst[done + t] = src[done + t];
}

// cooperative aligned constant fill over absolute float range [lo,hi)
__device__ __forceinline__ void coop_fill(float* __restrict__ base, long lo,
                                          long hi, float val, int t)
{
  long len = hi - lo;
  if (len <= 0) return;
  float* p = base + lo;
  int h = (int)(((16u - (unsigned)((unsigned long long)p & 15ull)) >> 2) & 3u);
  if ((long)h > len) h = (int)len;
  if (t < h) p[t] = val;
  long n4 = (len - h) >> 2;
  f32x4* d4 = (f32x4*)(p + h);
  f32x4 v = {val, val, val, val};
  for (long q = t; q < n4; q += BLOCK) d4[q] = v;
  long done = h + 4 * n4;
  int rem = (int)(len - done);
  if (t < rem) p[done + t] = val;
}

// K3: Rij passthrough (from L3) + idx passthrough + mask + block scan +
// LDS-staged compaction + aligned cooperative writes + pad fills.
__global__ void __launch_bounds__(BLOCK) k3_scatter_fill(
    const float* __restrict__ Rij, const int* __restrict__ idx_i,
    const int* __restrict__ idx_j, const int* __restrict__ offs,
    const int* __restrict__ nsr, float* __restrict__ out, long E, int nb)
{
  long b = blockIdx.x;
  int t = threadIdx.x;
  int lane = t & 63, wid = t >> 6;
  long base = b * (long)EPB + (long)t * EPT;
  long n = nsr[0];

  __shared__ float sR[3 * EPB];  // 12 KB
  __shared__ float sI[EPB];      // 4 KB
  __shared__ float sJ[EPB];      // 4 KB
  __shared__ int wsum[BLOCK / 64];

  float rr[12];
  int ii[EPT], jj[EPT];
  unsigned m = 0;
  int cnt = 0;
  if (base < E) {
    const f32x4* rp4 = (const f32x4*)(Rij + base * 3);
    f32x4 r0 = rp4[0], r1 = rp4[1], r2 = rp4[2];
    int4 ia = *(const int4*)(idx_i + base);
    int4 ja = *(const int4*)(idx_j + base);
    // Rij passthrough (L3-resident read -> HBM write)
    f32x4* op4 = (f32x4*)(out + base * 3);
    op4[0] = r0; op4[1] = r1; op4[2] = r2;
    rr[0] = r0.x; rr[1] = r0.y; rr[2] = r0.z; rr[3] = r0.w;
    rr[4] = r1.x; rr[5] = r1.y; rr[6] = r1.z; rr[7] = r1.w;
    rr[8] = r2.x; rr[9] = r2.y; rr[10] = r2.z; rr[11] = r2.w;
    ii[0] = ia.x; ii[1] = ia.y; ii[2] = ia.z; ii[3] = ia.w;
    jj[0] = ja.x; jj[1] = ja.y; jj[2] = ja.z; jj[3] = ja.w;
    // idx passthrough as float values
    f32x4 fi0 = {(float)ii[0], (float)ii[1], (float)ii[2], (float)ii[3]};
    f32x4 fj0 = {(float)jj[0], (float)jj[1], (float)jj[2], (float)jj[3]};
    *(f32x4*)(out + 3 * E + base) = fi0;
    *(f32x4*)(out + 4 * E + base) = fj0;
#pragma unroll
    for (int k = 0; k < EPT; ++k) {
      float x = rr[3 * k], y = rr[3 * k + 1], z = rr[3 * k + 2];
      float s = sqrtf(x * x + y * y + z * z);
      if (s <= CUTOFF) { m |= 1u << k; ++cnt; }
    }
  }

  // block scan of per-thread counts
  int sv = cnt;
#pragma unroll
  for (int d = 1; d < 64; d <<= 1) {
    int nn = __shfl_up(sv, d, 64);
    if (lane >= d) sv += nn;
  }
  if (lane == 63) wsum[wid] = sv;
  __syncthreads();
  int woff = 0, bsum = 0;
#pragma unroll
  for (int w = 0; w < BLOCK / 64; ++w) {
    int s = wsum[w];
    if (w < wid) woff += s;
    bsum += s;
  }
  int texcl = woff + sv - cnt;  // thread's exclusive offset within block

  // stage compacted edges into LDS in stable order
  if (base < E && m) {
    int p = texcl;
#pragma unroll
    for (int k = 0; k < EPT; ++k) {
      if (m & (1u << k)) {
        sR[3 * p + 0] = rr[3 * k + 0];
        sR[3 * p + 1] = rr[3 * k + 1];
        sR[3 * p + 2] = rr[3 * k + 2];
        sI[p] = (float)ii[k];
        sJ[p] = (float)jj[k];
        ++p;
      }
    }
  }
  __syncthreads();

  // cooperative aligned writes of the block's three contiguous runs
  long off = offs[b];
  coop_copy(out + 5 * E + 3 * off, sR, 3 * bsum, t);
  coop_copy(out + 8 * E + off, sI, bsum, t);
  coop_copy(out + 9 * E + off, sJ, bsum, t);

  // pad fills: three flat constant ranges, sliced across blocks, float4.
  {
    long len = 3 * (E - n);
    long share = ((len + nb - 1) / nb + 3) & ~3L;
    long lo = 5 * E + 3 * n + b * share;
    long hi = lo + share;
    long cap = 8 * E;
    if (hi > cap) hi = cap;
    coop_fill(out, lo, hi, 0.0f, t);
  }
  {
    long len = E - n;
    long share = ((len + nb - 1) / nb + 3) & ~3L;
    long lo = 8 * E + n + b * share;
    long hi = lo + share;
    long cap = 9 * E;
    if (hi > cap) hi = cap;
    coop_fill(out, lo, hi, -1.0f, t);
  }
  {
    long len = E - n;
    long share = ((len + nb - 1) / nb + 3) & ~3L;
    long lo = 9 * E + n + b * share;
    long hi = lo + share;
    long cap = 10 * E;
    if (hi > cap) hi = cap;
    coop_fill(out, lo, hi, -1.0f, t);
  }
}

extern "C" void kernel_launch(void* const* d_in, const int* in_sizes, int n_in,
                              void* d_out, int out_size, void* d_ws,
                              size_t ws_size, hipStream_t stream)
{
  const float* Rij = (const float*)d_in[0];
  const int* idx_i = (const int*)d_in[1];
  const int* idx_j = (const int*)d_in[2];
  long E = (long)in_sizes[1];
  float* out = (float*)d_out;

  int nb = (int)((E + EPB - 1) / EPB);
  int* counts = (int*)d_ws;  // nb ints, fully rewritten by K1 every call
  int* nsr = counts + nb;    // 1 int, written by K2 every call

  k1_count<<<nb, BLOCK, 0, stream>>>(Rij, counts, E);
  k2_scan<<<1, 1024, 0, stream>>>(counts, nb, nsr, out + 10 * E);
  k3_scatter_fill<<<nb, BLOCK, 0, stream>>>(Rij, idx_i, idx_j, counts, nsr,
                                            out, E, nb);
}

// Round 14
// 307.171 us; speedup vs baseline: 1.4512x; 1.0329x over previous
//
#include <hip/hip_runtime.h>

#define CUTOFF 1.6f
#define BLOCK 256
#define EPT 4
#define EPB (BLOCK * EPT)

typedef float f32x4 __attribute__((ext_vector_type(4)));

// K1: read Rij (float4), write Rij passthrough, per-block counts.
// Plain stores; cross-kernel visibility via the dispatch boundary
// (no fences — R8 lesson; no NT stores — R3/R4 lesson).
__global__ void __launch_bounds__(BLOCK) k1_count_copy(
    const float* __restrict__ Rij, float* __restrict__ outRij,
    int* __restrict__ counts, long E)
{
  long b = blockIdx.x;
  int t = threadIdx.x;
  long base = b * (long)EPB + (long)t * EPT;
  int cnt = 0;
  if (base < E) {  // E % 4 == 0 -> thread has all 4 edges or none
    const f32x4* rp4 = (const f32x4*)(Rij + base * 3);
    f32x4* op4 = (f32x4*)(outRij + base * 3);
    float rr[12];
#pragma unroll
    for (int q = 0; q < 3; ++q) {
      f32x4 v = rp4[q];
      op4[q] = v;
      rr[4 * q + 0] = v.x; rr[4 * q + 1] = v.y;
      rr[4 * q + 2] = v.z; rr[4 * q + 3] = v.w;
    }
#pragma unroll
    for (int k = 0; k < EPT; ++k) {
      float x = rr[3 * k], y = rr[3 * k + 1], z = rr[3 * k + 2];
      float s = sqrtf(x * x + y * y + z * z);
      cnt += (s <= CUTOFF) ? 1 : 0;
    }
  }
#pragma unroll
  for (int d = 32; d > 0; d >>= 1) cnt += __shfl_down(cnt, d, 64);
  __shared__ int ssum;
  if (t == 0) ssum = 0;
  __syncthreads();
  if ((t & 63) == 0) atomicAdd(&ssum, cnt);
  __syncthreads();
  if (t == 0) counts[b] = ssum;
}

// K2: single-block exclusive scan of block counts (in place); writes n_sr.
__global__ void __launch_bounds__(1024) k2_scan(
    int* __restrict__ counts, int nb, int* __restrict__ nsr,
    float* __restrict__ out_nsr)
{
  int t = threadIdx.x;
  int C = (nb + 1023) >> 10;
  int start = t * C;
  int end = min(start + C, nb);
  int sum = 0;
  for (int i = start; i < end; ++i) sum += counts[i];
  int lane = t & 63, wid = t >> 6;
  int v = sum;
#pragma unroll
  for (int d = 1; d < 64; d <<= 1) {
    int n = __shfl_up(v, d, 64);
    if (lane >= d) v += n;
  }
  __shared__ int wsum[16];
  if (lane == 63) wsum[wid] = v;
  __syncthreads();
  int woff = 0;
  for (int w = 0; w < wid; ++w) woff += wsum[w];
  int run = woff + v - sum;  // exclusive prefix of this thread
  for (int i = start; i < end; ++i) {
    int c = counts[i];
    counts[i] = run;
    run += c;
  }
  if (t == 1023) {  // run here == grand total
    nsr[0] = run;
    out_nsr[0] = (float)run;
  }
}

// cooperative aligned copy: dst[0..len) = src[0..len), float4 interior
__device__ __forceinline__ void coop_copy(float* __restrict__ dst,
                                          const float* __restrict__ src,
                                          int len, int t)
{
  int h = (int)(((16u - (unsigned)((unsigned long long)dst & 15ull)) >> 2) & 3u);
  if (h > len) h = len;
  if (t < h) dst[t] = src[t];
  int n4 = (len - h) >> 2;
  f32x4* d4 = (f32x4*)(dst + h);
  for (int q = t; q < n4; q += BLOCK) {
    int s = h + 4 * q;
    f32x4 v = {src[s], src[s + 1], src[s + 2], src[s + 3]};
    d4[q] = v;
  }
  int done = h + 4 * n4;
  int rem = len - done;
  if (t < rem) dst[done + t] = src[done + t];
}

// cooperative aligned constant fill over absolute float range [lo,hi)
__device__ __forceinline__ void coop_fill(float* __restrict__ base, long lo,
                                          long hi, float val, int t)
{
  long len = hi - lo;
  if (len <= 0) return;
  float* p = base + lo;
  int h = (int)(((16u - (unsigned)((unsigned long long)p & 15ull)) >> 2) & 3u);
  if ((long)h > len) h = (int)len;
  if (t < h) p[t] = val;
  long n4 = (len - h) >> 2;
  f32x4* d4 = (f32x4*)(p + h);
  f32x4 v = {val, val, val, val};
  for (long q = t; q < n4; q += BLOCK) d4[q] = v;
  long done = h + 4 * n4;
  int rem = (int)(len - done);
  if (t < rem) p[done + t] = val;
}

// K3: idx passthrough (float4), mask + block scan, LDS-staged compaction
// (20 KB -> high occupancy), aligned cooperative float4 output writes,
// fused vectorized pad fill.
__global__ void __launch_bounds__(BLOCK) k3_scatter_fill(
    const float* __restrict__ Rij, const int* __restrict__ idx_i,
    const int* __restrict__ idx_j, const int* __restrict__ offs,
    const int* __restrict__ nsr, float* __restrict__ out, long E, int nb)
{
  long b = blockIdx.x;
  int t = threadIdx.x;
  int lane = t & 63, wid = t >> 6;
  long base = b * (long)EPB + (long)t * EPT;
  long n = nsr[0];

  __shared__ float sR[3 * EPB];  // 12 KB
  __shared__ float sI[EPB];      // 4 KB
  __shared__ float sJ[EPB];      // 4 KB
  __shared__ int wsum[BLOCK / 64];

  float rr[12];
  int ii[EPT], jj[EPT];
  unsigned m = 0;
  int cnt = 0;
  if (base < E) {
    const f32x4* rp4 = (const f32x4*)(Rij + base * 3);
#pragma unroll
    for (int q = 0; q < 3; ++q) {
      f32x4 v = rp4[q];
      rr[4 * q + 0] = v.x; rr[4 * q + 1] = v.y;
      rr[4 * q + 2] = v.z; rr[4 * q + 3] = v.w;
    }
    int4 ia = *(const int4*)(idx_i + base);
    int4 ja = *(const int4*)(idx_j + base);
    ii[0] = ia.x; ii[1] = ia.y; ii[2] = ia.z; ii[3] = ia.w;
    jj[0] = ja.x; jj[1] = ja.y; jj[2] = ja.z; jj[3] = ja.w;
    // idx passthrough as float values (normal float4 stores)
    f32x4 fi0 = {(float)ii[0], (float)ii[1], (float)ii[2], (float)ii[3]};
    f32x4 fj0 = {(float)jj[0], (float)jj[1], (float)jj[2], (float)jj[3]};
    *(f32x4*)(out + 3 * E + base) = fi0;
    *(f32x4*)(out + 4 * E + base) = fj0;
#pragma unroll
    for (int k = 0; k < EPT; ++k) {
      float x = rr[3 * k], y = rr[3 * k + 1], z = rr[3 * k + 2];
      float s = sqrtf(x * x + y * y + z * z);
      if (s <= CUTOFF) { m |= 1u << k; ++cnt; }
    }
  }

  // block scan of per-thread counts
  int sv = cnt;
#pragma unroll
  for (int d = 1; d < 64; d <<= 1) {
    int nn = __shfl_up(sv, d, 64);
    if (lane >= d) sv += nn;
  }
  if (lane == 63) wsum[wid] = sv;
  __syncthreads();
  int woff = 0, bsum = 0;
#pragma unroll
  for (int w = 0; w < BLOCK / 64; ++w) {
    int s = wsum[w];
    if (w < wid) woff += s;
    bsum += s;
  }
  int texcl = woff + sv - cnt;  // thread's exclusive offset within block

  // stage compacted edges into LDS in stable order
  if (base < E && m) {
    int p = texcl;
#pragma unroll
    for (int k = 0; k < EPT; ++k) {
      if (m & (1u << k)) {
        sR[3 * p + 0] = rr[3 * k + 0];
        sR[3 * p + 1] = rr[3 * k + 1];
        sR[3 * p + 2] = rr[3 * k + 2];
        sI[p] = (float)ii[k];
        sJ[p] = (float)jj[k];
        ++p;
      }
    }
  }
  __syncthreads();

  // cooperative aligned writes of the block's three contiguous runs
  long off = offs[b];
  coop_copy(out + 5 * E + 3 * off, sR, 3 * bsum, t);
  coop_copy(out + 8 * E + off, sI, bsum, t);
  coop_copy(out + 9 * E + off, sJ, bsum, t);

  // pad fills: three flat constant ranges, sliced across blocks, float4.
  {
    long len = 3 * (E - n);
    long share = ((len + nb - 1) / nb + 3) & ~3L;
    long lo = 5 * E + 3 * n + b * share;
    long hi = lo + share;
    long cap = 8 * E;
    if (hi > cap) hi = cap;
    coop_fill(out, lo, hi, 0.0f, t);
  }
  {
    long len = E - n;
    long share = ((len + nb - 1) / nb + 3) & ~3L;
    long lo = 8 * E + n + b * share;
    long hi = lo + share;
    long cap = 9 * E;
    if (hi > cap) hi = cap;
    coop_fill(out, lo, hi, -1.0f, t);
  }
  {
    long len = E - n;
    long share = ((len + nb - 1) / nb + 3) & ~3L;
    long lo = 9 * E + n + b * share;
    long hi = lo + share;
    long cap = 10 * E;
    if (hi > cap) hi = cap;
    coop_fill(out, lo, hi, -1.0f, t);
  }
}

extern "C" void kernel_launch(void* const* d_in, const int* in_sizes, int n_in,
                              void* d_out, int out_size, void* d_ws,
                              size_t ws_size, hipStream_t stream)
{
  const float* Rij = (const float*)d_in[0];
  const int* idx_i = (const int*)d_in[1];
  const int* idx_j = (const int*)d_in[2];
  long E = (long)in_sizes[1];
  float* out = (float*)d_out;

  int nb = (int)((E + EPB - 1) / EPB);
  int* counts = (int*)d_ws;  // nb ints, fully rewritten by K1 every call
  int* nsr = counts + nb;    // 1 int, written by K2 every call

  k1_count_copy<<<nb, BLOCK, 0, stream>>>(Rij, out, counts, E);
  k2_scan<<<1, 1024, 0, stream>>>(counts, nb, nsr, out + 10 * E);
  k3_scatter_fill<<<nb, BLOCK, 0, stream>>>(Rij, idx_i, idx_j, counts, nsr,
                                            out, E, nb);
}